// Round 1
// baseline (446.567 us; speedup 1.0000x reference)
//
#include <hip/hip_runtime.h>

// Fused FWHT: out0 = FWHT_axis1(x), out1 = FWHT_axis2(out0).
// x: (64, 64, 64, 128) fp32; strides (elements): b0=524288, i=8192, j=128, c=1.
//
// One block per (b0, 4-channel chunk): 64 * 32 = 2048 blocks, 256 threads.
// Pass 1: thread (j, cl) holds the full i-line in registers, FWHT, store out0.
// Transpose i<->j through a 64 KiB XOR-swizzled LDS tile (bank-conflict-free).
// Pass 2: thread (i, cl) holds the full j-line, FWHT, store out1.
//
// The 32 sibling c-chunk blocks of each b0 are pinned to one XCD via a
// chunked bijective swizzle (2048 = 8 XCDs * 256) so their 16B sub-line
// reads/writes merge in that XCD's L2 into full-line HBM transactions.

__device__ __forceinline__ void fwht64(float v[64]) {
    // identical pairing/order to the reference butterflies
#pragma unroll
    for (int sh = 0; sh < 6; ++sh) {
        const int h = 1 << sh;
#pragma unroll
        for (int s = 0; s < 64; s += 2 * h) {
#pragma unroll
            for (int t = 0; t < h; ++t) {
                const float a = v[s + t];
                const float b = v[s + t + h];
                v[s + t]     = a + b;
                v[s + t + h] = a - b;
            }
        }
    }
}

__global__ __launch_bounds__(256) void fwht_fused(const float* __restrict__ in,
                                                  float* __restrict__ out0,
                                                  float* __restrict__ out1) {
    __shared__ float lds[64 * 256];   // [i][ (j*4+cl) ^ ((i&7)<<2) ]  = 64 KiB

    // XCD-chunked bijective swizzle: XCD k gets logical blocks [k*256, (k+1)*256)
    const int bid = blockIdx.x;
    const int lb  = (bid & 7) * 256 + (bid >> 3);

    const int b0 = lb >> 5;            // 0..63
    const int c0 = (lb & 31) * 4;      // channel-chunk base: 0,4,...,124

    const int t  = threadIdx.x;        // 0..255
    const int j  = t >> 2;             // 0..63
    const int cl = t & 3;              // 0..3

    // ---- pass 1: FWHT over axis i (stride 8192) ----
    const int base = b0 * 524288 + j * 128 + (c0 + cl);

    float v[64];
#pragma unroll
    for (int i = 0; i < 64; ++i)
        v[i] = in[base + i * 8192];

    fwht64(v);

#pragma unroll
    for (int i = 0; i < 64; ++i)
        out0[base + i * 8192] = v[i];

    // scatter i-lines into LDS, XOR-swizzled (2-way max -> conflict-free)
#pragma unroll
    for (int i = 0; i < 64; ++i)
        lds[i * 256 + (t ^ ((i & 7) << 2))] = v[i];

    __syncthreads();

    // ---- pass 2: FWHT over axis j (stride 128) ----
    const int i2  = t >> 2;            // 0..63
    const int cl2 = t & 3;             // 0..3

    float w[64];
#pragma unroll
    for (int jj = 0; jj < 64; ++jj)
        w[jj] = lds[i2 * 256 + ((jj * 4 + cl2) ^ ((i2 & 7) << 2))];

    fwht64(w);

    const int base1 = b0 * 524288 + i2 * 8192 + (c0 + cl2);
#pragma unroll
    for (int jj = 0; jj < 64; ++jj)
        out1[base1 + jj * 128] = w[jj];
}

extern "C" void kernel_launch(void* const* d_in, const int* in_sizes, int n_in,
                              void* d_out, int out_size, void* d_ws, size_t ws_size,
                              hipStream_t stream) {
    const float* x = (const float*)d_in[0];
    float* out0 = (float*)d_out;                 // trans_im1: 64*64*64*128 floats
    float* out1 = out0 + 64 * 64 * 64 * 128;     // trans_im2

    // 64 b0 * 32 c-chunks = 2048 blocks of 256 threads
    fwht_fused<<<2048, 256, 0, stream>>>(x, out0, out1);
}

// Round 5
// 356.912 us; speedup vs baseline: 1.2512x; 1.2512x over previous
//
#include <hip/hip_runtime.h>

// x: (64, 64, 64, 128) fp32; element strides: b0=524288, i=8192, j=128, c=1.
// out0 = FWHT over axis 1 (i), out1 = FWHT over axis 2 (j) of out0.
//
// Two-pass structure (each pass writes only FULL cache lines — the fused
// c-thin-tile version measured 1.9x write amplification from 16B granules).
// Each thread transforms one length-64 line, holding it as f32x2[64] in
// registers; a wave's 64 lanes cover a full 128-channel row => every global
// load/store instruction is 512 B contiguous.
//
// Pass 1 (axis i, stride 8192): NT-loads x (read-once) so L2 keeps out0.
// Pass 2 (axis j, stride 128):  runs b0 in REVERSED order per XCD so it
// starts on the out0 region pass 1 wrote last (still L2-resident), and
// NT-stores out1 (never re-read).
// Both passes use the same XCD-chunked block swizzle so b0 -> XCD matches.

typedef float f32x2 __attribute__((ext_vector_type(2)));   // native vector:
// __builtin_nontemporal_* accepts it (HIP_vector_type float2 is a struct and
// is rejected -- round-2 compile error).

template <int T2, int F2, bool REVERSE, bool NTLOAD, bool NTSTORE>
__global__ __launch_bounds__(256) void fwht64_v2(const f32x2* __restrict__ in,
                                                 f32x2* __restrict__ out) {
    // grid = 1024 blocks: xcd = bid&7 (HW round-robin), slot = bid>>3 (0..127)
    // XCD k owns b0 in [8k, 8k+8); 16 blocks per b0 (4 rows of the fixed axis
    // each, full 64-f32x2 channel row).
    const int bid  = blockIdx.x;
    const int xcd  = bid & 7;
    const int slot = bid >> 3;
    int b0l = slot >> 4;                    // 0..7
    if (REVERSE) b0l = 7 - b0l;
    const int b0   = xcd * 8 + b0l;
    const int mblk = slot & 15;

    const int t  = threadIdx.x;
    const int c2 = t & 63;                  // f32x2 channel index (128 c = 64 pairs)
    const int m  = mblk * 4 + (t >> 6);     // fixed-axis coordinate, 0..63

    const int base = b0 * 262144 + m * F2 + c2;   // f32x2 units
    const f32x2* __restrict__ pin  = in  + base;
    f32x2*       __restrict__ pout = out + base;

    f32x2 v[64];
#pragma unroll
    for (int k = 0; k < 64; ++k) {
        if (NTLOAD) v[k] = __builtin_nontemporal_load(&pin[k * T2]);
        else        v[k] = pin[k * T2];
    }

    // 6 butterfly stages, identical pairing/order to the reference:
    // for h in {1,2,4,8,16,32}: (v[s+t], v[s+t+h]) -> (a+b, a-b)
#pragma unroll
    for (int sh = 0; sh < 6; ++sh) {
        const int h = 1 << sh;
#pragma unroll
        for (int s = 0; s < 64; s += 2 * h) {
#pragma unroll
            for (int u = 0; u < h; ++u) {
                const f32x2 a = v[s + u];
                const f32x2 b = v[s + u + h];
                v[s + u]     = a + b;
                v[s + u + h] = a - b;
            }
        }
    }

#pragma unroll
    for (int k = 0; k < 64; ++k) {
        if (NTSTORE) __builtin_nontemporal_store(v[k], &pout[k * T2]);
        else         pout[k * T2] = v[k];
    }
}

extern "C" void kernel_launch(void* const* d_in, const int* in_sizes, int n_in,
                              void* d_out, int out_size, void* d_ws, size_t ws_size,
                              hipStream_t stream) {
    const f32x2* x2 = (const f32x2*)d_in[0];
    f32x2* out0 = (f32x2*)d_out;                     // trans_im1
    f32x2* out1 = out0 + 64 * 64 * 64 * 64;          // trans_im2 (f32x2 units)

    // 64 b0 * 16 blocks = 1024 blocks of 256 threads; each thread one line.
    // Pass 1: transform axis i (stride 8192 fl = 4096 fl2), fixed j (64 fl2).
    fwht64_v2<4096, 64, false, true, false><<<1024, 256, 0, stream>>>(x2, out0);
    // Pass 2: transform axis j (stride 128 fl = 64 fl2), fixed i (4096 fl2),
    // reversed b0 per XCD for L2 reuse of freshly-written out0; NT out1.
    fwht64_v2<64, 4096, true, false, true><<<1024, 256, 0, stream>>>(out0, out1);
}